// Round 1
// baseline (564.477 us; speedup 1.0000x reference)
//
#include <hip/hip_runtime.h>
#include <stdint.h>

#define FIELD 39
#define VOCAB 100000
#define EMB   32
#define NH1   32
#define NH2   32
#define NBATCH 16384

typedef __attribute__((ext_vector_type(8))) short short8;
typedef __attribute__((ext_vector_type(4))) float f32x4;
typedef __attribute__((ext_vector_type(4))) unsigned int u32x4;

__device__ __host__ inline unsigned short f2bf(float f) {
    union { float f; unsigned u; } v; v.f = f;
    unsigned r = v.u + 0x7FFF + ((v.u >> 16) & 1);
    return (unsigned short)(r >> 16);
}

// Pack lin1_w (fp32 [1248][32]) into bf16 B-fragment layout:
// bpack[f][c][g][h][e] = bf16(lin1_w[(f*32 + 8*g + e)*32 + c*16 + h])
// offset = f*1024 + c*512 + g*128 + h*8 + e   (ushort elements)
__global__ void prep_bpack(const float* __restrict__ lin1_w,
                           unsigned short* __restrict__ bpack) {
    int t = blockIdx.x * 256 + threadIdx.x;
    const int total = FIELD * 2 * 4 * 16 * 8;   // 39936
    if (t >= total) return;
    int e = t & 7;
    int h = (t >> 3) & 15;
    int g = (t >> 7) & 3;
    int c = (t >> 9) & 1;
    int f = t >> 10;
    int k = f * 32 + 8 * g + e;
    bpack[t] = f2bf(lin1_w[k * 32 + c * 16 + h]);
}

__global__ __launch_bounds__(64)
void deepfm_main(const int* __restrict__ Xi, const float* __restrict__ Xv,
                 const float* __restrict__ W1, const float* __restrict__ W2,
                 const unsigned short* __restrict__ bpack,
                 const float* __restrict__ lin1_b, const float* __restrict__ lin2_w,
                 const float* __restrict__ lin2_b, const float* __restrict__ bias,
                 float* __restrict__ out) {
    __shared__ int   idx_s[16 * FIELD];
    __shared__ float xv_s[16 * FIELD];
    __shared__ __align__(16) float w2_s[NH1 * NH2];
    __shared__ float x_s[16 * 33];

    const int lane = threadIdx.x;      // 0..63
    const int r    = lane & 15;        // row-local (MFMA m index)
    const int g    = lane >> 4;        // k-group 0..3 (dims 8g..8g+7)
    const int row0 = blockIdx.x * 16;

    // Stage this tile's indices/values + lin2_w into LDS (coalesced).
    for (int i = lane; i < 16 * FIELD; i += 64) {
        idx_s[i] = Xi[row0 * FIELD + i];
        xv_s[i]  = Xv[row0 * FIELD + i];
    }
    for (int i = lane; i < NH1 * NH2; i += 64) w2_s[i] = lin2_w[i];
    __syncthreads();

    f32x4 acc0 = {0.f, 0.f, 0.f, 0.f};  // out cols 0..15
    f32x4 acc1 = {0.f, 0.f, 0.f, 0.f};  // out cols 16..31
    f32x4 sa = {0.f,0.f,0.f,0.f}, sb = {0.f,0.f,0.f,0.f};
    f32x4 qa = {0.f,0.f,0.f,0.f}, qb = {0.f,0.f,0.f,0.f};
    float first = 0.f;

    // --- 3-slot software pipeline over fields ---
    f32x4 pa0, pa1, pa2, pb0, pb1, pb2;
    u32x4 q00, q01, q02, q10, q11, q12;
    float w1v0, w1v1, w1v2, xvv0, xvv1, xvv2;

#define ISSUE(F, PA, PB, Q0, Q1, WV, XVV) {                              \
        int f_ = (F) < FIELD ? (F) : (FIELD - 1);                        \
        int ii = idx_s[r * FIELD + f_];                                  \
        XVV = xv_s[r * FIELD + f_];                                      \
        const float* w2p = W2 + (size_t)(f_ * VOCAB + ii) * EMB + g * 8; \
        PA = *(const f32x4*)(w2p);                                       \
        PB = *(const f32x4*)(w2p + 4);                                   \
        WV = W1[f_ * VOCAB + ii];                                        \
        const unsigned short* bp = bpack + f_ * 1024 + g * 128 + r * 8;  \
        Q0 = *(const u32x4*)(bp);                                        \
        Q1 = *(const u32x4*)(bp + 512);                                  \
    }

#define COMPUTE(PA, PB, Q0, Q1, WV, XVV) {                               \
        f32x4 ea = PA * XVV;                                             \
        f32x4 eb = PB * XVV;                                             \
        sa += ea; qa += ea * ea;                                         \
        sb += eb; qb += eb * eb;                                         \
        unsigned p0, p1, p2, p3;                                         \
        asm("v_cvt_pk_bf16_f32 %0, %1, %2" : "=v"(p0) : "v"(ea.x), "v"(ea.y)); \
        asm("v_cvt_pk_bf16_f32 %0, %1, %2" : "=v"(p1) : "v"(ea.z), "v"(ea.w)); \
        asm("v_cvt_pk_bf16_f32 %0, %1, %2" : "=v"(p2) : "v"(eb.x), "v"(eb.y)); \
        asm("v_cvt_pk_bf16_f32 %0, %1, %2" : "=v"(p3) : "v"(eb.z), "v"(eb.w)); \
        u32x4 afu = {p0, p1, p2, p3};                                    \
        short8 a8 = __builtin_bit_cast(short8, afu);                     \
        acc0 = __builtin_amdgcn_mfma_f32_16x16x32_bf16(                  \
                   a8, __builtin_bit_cast(short8, Q0), acc0, 0, 0, 0);   \
        acc1 = __builtin_amdgcn_mfma_f32_16x16x32_bf16(                  \
                   a8, __builtin_bit_cast(short8, Q1), acc1, 0, 0, 0);   \
        first += WV * XVV;                                               \
    }

    ISSUE(0, pa0, pb0, q00, q10, w1v0, xvv0);
    ISSUE(1, pa1, pb1, q01, q11, w1v1, xvv1);
    for (int i = 0; i < 13; ++i) {
        int f = 3 * i;
        ISSUE(f + 2, pa2, pb2, q02, q12, w1v2, xvv2);
        COMPUTE(pa0, pb0, q00, q10, w1v0, xvv0);
        ISSUE(f + 3, pa0, pb0, q00, q10, w1v0, xvv0);
        COMPUTE(pa1, pb1, q01, q11, w1v1, xvv1);
        ISSUE(f + 4, pa1, pb1, q01, q11, w1v1, xvv1);
        COMPUTE(pa2, pb2, q02, q12, w1v2, xvv2);
    }
#undef ISSUE
#undef COMPUTE

    // --- FM second-order: sec = sum_d 0.5*(s_d^2 - sq_d), reduce 4 lanes/row ---
    float sec = 0.f;
#pragma unroll
    for (int j = 0; j < 4; ++j) {
        sec += 0.5f * (sa[j] * sa[j] - qa[j]);
        sec += 0.5f * (sb[j] * sb[j] - qb[j]);
    }
    sec += __shfl_xor(sec, 16);
    sec += __shfl_xor(sec, 32);

    // --- layer-1 bias + relu, C/D layout: col = lane&15, row = 4*(lane>>4)+reg ---
    float b1a = lin1_b[r];
    float b1b = lin1_b[16 + r];
#pragma unroll
    for (int j = 0; j < 4; ++j) {
        int rw = g * 4 + j;
        x_s[rw * 33 + r]      = fmaxf(acc0[j] + b1a, 0.f);
        x_s[rw * 33 + 16 + r] = fmaxf(acc1[j] + b1b, 0.f);
    }
    __syncthreads();

    // --- layer-2 (32x32) + relu + sum: lane (r,g) computes h2 in {8g..8g+7} ---
    f32x4 y0 = { lin2_b[g*8+0], lin2_b[g*8+1], lin2_b[g*8+2], lin2_b[g*8+3] };
    f32x4 y1 = { lin2_b[g*8+4], lin2_b[g*8+5], lin2_b[g*8+6], lin2_b[g*8+7] };
#pragma unroll
    for (int h = 0; h < 32; ++h) {
        float xh = x_s[r * 33 + h];
        f32x4 wA = *(const f32x4*)&w2_s[h * 32 + g * 8];
        f32x4 wB = *(const f32x4*)&w2_s[h * 32 + g * 8 + 4];
        y0 += xh * wA;
        y1 += xh * wB;
    }
    float dsum = 0.f;
#pragma unroll
    for (int j = 0; j < 4; ++j) {
        dsum += fmaxf(y0[j], 0.f);
        dsum += fmaxf(y1[j], 0.f);
    }
    dsum += __shfl_xor(dsum, 16);
    dsum += __shfl_xor(dsum, 32);

    if (g == 0) out[row0 + r] = first + sec + dsum + bias[0];
}

extern "C" void kernel_launch(void* const* d_in, const int* in_sizes, int n_in,
                              void* d_out, int out_size, void* d_ws, size_t ws_size,
                              hipStream_t stream) {
    const int*   Xi   = (const int*)d_in[0];
    const float* Xv   = (const float*)d_in[1];
    const float* W1   = (const float*)d_in[2];
    const float* W2   = (const float*)d_in[3];
    const float* l1w  = (const float*)d_in[4];
    const float* l1b  = (const float*)d_in[5];
    const float* l2w  = (const float*)d_in[6];
    const float* l2b  = (const float*)d_in[7];
    const float* bias = (const float*)d_in[8];
    unsigned short* bpack = (unsigned short*)d_ws;

    hipLaunchKernelGGL(prep_bpack, dim3(156), dim3(256), 0, stream, l1w, bpack);
    hipLaunchKernelGGL(deepfm_main, dim3(NBATCH / 16), dim3(64), 0, stream,
                       Xi, Xv, W1, W2, bpack, l1b, l2w, l2b, bias, (float*)d_out);
}